// Round 2
// baseline (624.216 us; speedup 1.0000x reference)
//
#include <hip/hip_runtime.h>
#include <stdint.h>

// Problem constants (QuantizedLinear: B=4, S=2048, IN=4096, OUT=4096, OUTLIER=128)
#define IN_F  4096
#define OUT_F 4096
#define OUTL  128
#define QIN   (IN_F - OUTL)   // 3968
#define MTOT  8192            // B*S
#define BM 128
#define BN 128
#define BK 32

typedef unsigned short u16;
typedef __bf16 bf16x8 __attribute__((ext_vector_type(8)));
typedef float  f32x4  __attribute__((ext_vector_type(4)));

__device__ __forceinline__ u16 f2b(float f) {
  union { float f; uint32_t i; } v; v.f = f;
  uint32_t r = v.i + 0x7fffu + ((v.i >> 16) & 1u);  // round-to-nearest-even
  return (u16)(r >> 16);
}

// ---------------------------------------------------------------------------
// Kernel 1a: cast activation fp32 -> bf16. 4 elements/thread, float4 loads.
// ---------------------------------------------------------------------------
__global__ __launch_bounds__(256) void prep_a(const float* __restrict__ A,
                                              u16* __restrict__ Ab) {
  const size_t i4 = (size_t)blockIdx.x * 256 + threadIdx.x;
  const float4 v = ((const float4*)A)[i4];
  ushort4 o;
  o.x = f2b(v.x); o.y = f2b(v.y); o.z = f2b(v.z); o.w = f2b(v.w);
  ((ushort4*)Ab)[i4] = o;
}

// ---------------------------------------------------------------------------
// Kernel 1b: materialize permuted bf16 weight Wp[o, i] = out_w[o, invp[i]]
//   out_w[o, j] = j < QIN ? qw[o,j] * alpha[o] : fpw[o, j-QIN]
// Inputs are fp32 per the reference; output bf16 for MFMA.
// ---------------------------------------------------------------------------
__global__ __launch_bounds__(256) void prep_w(const float* __restrict__ qw,
                                              const float* __restrict__ fpw,
                                              const float* __restrict__ alpha,
                                              const int* __restrict__ invp,
                                              u16* __restrict__ W) {
  const int o = blockIdx.y;
  const int i = blockIdx.x * 256 + threadIdx.x;
  const int j = invp[i];
  float v;
  if (j < QIN) v = qw[(size_t)o * QIN + j] * alpha[o];
  else         v = fpw[(size_t)o * OUTL + (j - QIN)];
  W[(size_t)o * IN_F + i] = f2b(v);
}

// ---------------------------------------------------------------------------
// Kernel 2: m97-structure bf16 GEMM, B^T layout.
//   C[m,n] = sum_k A[m,k] * W[n,k] + bias[n]   (C fp32 out)
// 256 threads = 4 waves (2x2), each wave computes 64x64 via 4x4 of 16x16x32.
// global_load_lds width=16 staging; LDS row stride = BK (no pad: required by
// the wave-uniform-base + lane*16 LDS scatter semantics).
// ---------------------------------------------------------------------------
#define GLDS(g, l)                                                              \
  __builtin_amdgcn_global_load_lds(                                             \
      (const __attribute__((address_space(1))) void*)(g),                       \
      (__attribute__((address_space(3))) void*)(l), 16, 0, 0)

__global__ __launch_bounds__(256) void gemm_bt(
    const u16* __restrict__ A,      // MTOT x IN_F bf16 (prepped)
    const u16* __restrict__ W,      // OUT_F x IN_F bf16 (prepped)
    const float* __restrict__ bias, // OUT_F fp32
    float* __restrict__ C) {        // MTOT x OUT_F fp32
  __shared__ u16 As[BM * BK];  // 8 KB
  __shared__ u16 Bs[BN * BK];  // 8 KB

  const int tid  = threadIdx.x;
  const int wave = tid >> 6;
  const int lane = tid & 63;
  const int bn = blockIdx.x, bm = blockIdx.y;
  const int wm = (wave >> 1) * 64;  // wave's M offset in tile
  const int wn = (wave & 1)  * 64;  // wave's N offset in tile

  // Staging: wave stages tile rows [wave*32, wave*32+32) for both A and B,
  // 2 instructions x 16 rows each. Lane l covers row (l>>2), 16B chunk (l&3).
  const int srow = wave * 32 + (lane >> 2);
  const int scol = (lane & 3) * 8;  // bf16 elements
  const u16* Ag = A + (size_t)(bm * BM + srow) * IN_F + scol;
  const u16* Wg = W + (size_t)(bn * BN + srow) * IN_F + scol;
  u16* AsW = (u16*)As + (wave * 32) * BK;  // wave-uniform LDS base
  u16* BsW = (u16*)Bs + (wave * 32) * BK;

  f32x4 acc[4][4];
#pragma unroll
  for (int mi = 0; mi < 4; ++mi)
#pragma unroll
    for (int ni = 0; ni < 4; ++ni) acc[mi][ni] = (f32x4){0.f, 0.f, 0.f, 0.f};

  const int fr = lane & 15;  // fragment row (m for A, n for B)
  const int fq = lane >> 4;  // quad -> k offset = fq*8

  for (int kt = 0; kt < IN_F; kt += BK) {
    __syncthreads();  // previous iteration's ds_reads done before overwrite
    GLDS(Ag + kt,              AsW);
    GLDS(Ag + kt + 16 * IN_F,  AsW + 16 * BK);
    GLDS(Wg + kt,              BsW);
    GLDS(Wg + kt + 16 * IN_F,  BsW + 16 * BK);
    __syncthreads();  // compiler emits s_waitcnt vmcnt(0) before s_barrier

    bf16x8 af[4], bg[4];
#pragma unroll
    for (int mi = 0; mi < 4; ++mi)
      af[mi] = *(const bf16x8*)&As[(wm + mi * 16 + fr) * BK + fq * 8];
#pragma unroll
    for (int ni = 0; ni < 4; ++ni)
      bg[ni] = *(const bf16x8*)&Bs[(wn + ni * 16 + fr) * BK + fq * 8];
#pragma unroll
    for (int mi = 0; mi < 4; ++mi)
#pragma unroll
      for (int ni = 0; ni < 4; ++ni)
        acc[mi][ni] = __builtin_amdgcn_mfma_f32_16x16x32_bf16(
            af[mi], bg[ni], acc[mi][ni], 0, 0, 0);
  }

  // Epilogue: C/D layout col = lane&15 (n), row = (lane>>4)*4 + reg (m).
#pragma unroll
  for (int ni = 0; ni < 4; ++ni) {
    const int n = bn * BN + wn + ni * 16 + fr;
    const float bv = bias[n];
#pragma unroll
    for (int mi = 0; mi < 4; ++mi) {
      const int m0 = bm * BM + wm + mi * 16 + fq * 4;
#pragma unroll
      for (int rr = 0; rr < 4; ++rr)
        C[(size_t)(m0 + rr) * OUT_F + n] = acc[mi][ni][rr] + bv;
    }
  }
}

extern "C" void kernel_launch(void* const* d_in, const int* in_sizes, int n_in,
                              void* d_out, int out_size, void* d_ws, size_t ws_size,
                              hipStream_t stream) {
  const float* input = (const float*)d_in[0];  // (4,2048,4096) fp32
  const float* qw    = (const float*)d_in[1];  // (4096,3968) fp32
  const float* fpw   = (const float*)d_in[2];  // (4096,128) fp32
  const float* alpha = (const float*)d_in[3];  // (4096,1) fp32
  const float* bias  = (const float*)d_in[4];  // (4096,) fp32
  const int*   invp  = (const int*)d_in[5];    // (4096,) int32

  u16* Ab = (u16*)d_ws;                               // 8192*4096*2 = 64 MB
  u16* W  = (u16*)((char*)d_ws + (size_t)MTOT * IN_F * 2);  // +32 MB
  float* out = (float*)d_out;                         // (4,2048,4096) fp32

  prep_a<<<(MTOT * IN_F / 4) / 256, 256, 0, stream>>>(input, Ab);

  dim3 pgrid(IN_F / 256, OUT_F);
  prep_w<<<pgrid, dim3(256), 0, stream>>>(qw, fpw, alpha, invp, W);

  dim3 ggrid(OUT_F / BN, MTOT / BM);  // (32, 64)
  gemm_bt<<<ggrid, dim3(256), 0, stream>>>(Ab, W, bias, out);
}

// Round 3
// 575.712 us; speedup vs baseline: 1.0842x; 1.0842x over previous
//
#include <hip/hip_runtime.h>
#include <stdint.h>

// Problem constants (QuantizedLinear: B=4, S=2048, IN=4096, OUT=4096, OUTLIER=128)
#define IN_F  4096
#define OUT_F 4096
#define OUTL  128
#define QIN   (IN_F - OUTL)   // 3968
#define MTOT  8192            // B*S
#define BM 128
#define BN 128
#define BK 32

typedef unsigned short u16;
typedef __bf16 bf16x8 __attribute__((ext_vector_type(8)));
typedef float  f32x4  __attribute__((ext_vector_type(4)));

__device__ __forceinline__ u16 f2b(float f) {
  union { float f; uint32_t i; } v; v.f = f;
  uint32_t r = v.i + 0x7fffu + ((v.i >> 16) & 1u);  // round-to-nearest-even
  return (u16)(r >> 16);
}

// ---------------------------------------------------------------------------
// Fused prep: blocks [0, NA) cast activation fp32->bf16 (float4 streaming);
// blocks [NA, NA+OUT_F) build one permuted bf16 weight row each, staging the
// qw row in LDS so every global read is coalesced float4 and every store is a
// coalesced 16B uint4.
// ---------------------------------------------------------------------------
#define NA_BLOCKS (MTOT * IN_F / 4 / 256)  // 32768

__global__ __launch_bounds__(256) void prep_fused(
    const float* __restrict__ A, u16* __restrict__ Ab,
    const float* __restrict__ qw, const float* __restrict__ fpw,
    const float* __restrict__ alpha, const int* __restrict__ invp,
    u16* __restrict__ W) {
  __shared__ float qs[QIN];   // 15872 B
  __shared__ float fs[OUTL];  // 512 B
  const int tid = threadIdx.x;

  if (blockIdx.x < NA_BLOCKS) {  // ---- activation cast ----
    const size_t i4 = (size_t)blockIdx.x * 256 + tid;
    const float4 v = ((const float4*)A)[i4];
    ushort4 o;
    o.x = f2b(v.x); o.y = f2b(v.y); o.z = f2b(v.z); o.w = f2b(v.w);
    ((ushort4*)Ab)[i4] = o;
    return;
  }
  // ---- weight row build ----
  const int o = blockIdx.x - NA_BLOCKS;
  const float a = alpha[o];
  const float4* qrow = (const float4*)(qw + (size_t)o * QIN);
#pragma unroll
  for (int k = 0; k < 4; ++k) {
    const int idx = tid + k * 256;
    if (idx < QIN / 4) ((float4*)qs)[idx] = qrow[idx];
  }
  if (tid < OUTL / 4)
    ((float4*)fs)[tid] = ((const float4*)(fpw + (size_t)o * OUTL))[tid];
  __syncthreads();

  const int i0 = tid * 16;
  u16 vals[16];
#pragma unroll
  for (int q = 0; q < 4; ++q) {
    const int4 jj = ((const int4*)invp)[i0 / 4 + q];
    const int j[4] = {jj.x, jj.y, jj.z, jj.w};
#pragma unroll
    for (int e = 0; e < 4; ++e) {
      const float v = (j[e] < QIN) ? qs[j[e]] * a : fs[j[e] - QIN];
      vals[q * 4 + e] = f2b(v);
    }
  }
  uint4* dst = (uint4*)(W + (size_t)o * IN_F);
  dst[tid * 2]     = *(const uint4*)&vals[0];
  dst[tid * 2 + 1] = *(const uint4*)&vals[8];
}

// ---------------------------------------------------------------------------
// Kernel 2: m97-structure bf16 GEMM, B^T layout, XOR-swizzled LDS.
//   C[m,n] = sum_k A[m,k] * W[n,k] + bias[n]   (C fp32 out)
// LDS layout: row r (64 B) holds its 16B chunk c at slot c ^ ((r>>2)&3).
// A fragment read (16 lanes x 16B) then covers all 8 bank-quads exactly
// twice -> 2-way aliasing = conflict-free (m136). Staging implements the
// swizzle by permuting WHICH global chunk each lane fetches (same 64B lines,
// coalescing preserved; LDS dest stays uniform-base + lane*16).
// ---------------------------------------------------------------------------
#define GLDS(g, l)                                                              \
  __builtin_amdgcn_global_load_lds(                                             \
      (const __attribute__((address_space(1))) void*)(g),                       \
      (__attribute__((address_space(3))) void*)(l), 16, 0, 0)

__global__ __launch_bounds__(256) void gemm_bt(
    const u16* __restrict__ A,      // MTOT x IN_F bf16 (prepped)
    const u16* __restrict__ W,      // OUT_F x IN_F bf16 (prepped)
    const float* __restrict__ bias, // OUT_F fp32
    float* __restrict__ C) {        // MTOT x OUT_F fp32
  __shared__ u16 As[BM * BK];  // 8 KB
  __shared__ u16 Bs[BN * BK];  // 8 KB

  const int tid  = threadIdx.x;
  const int wave = tid >> 6;
  const int lane = tid & 63;
  const int bn = blockIdx.x, bm = blockIdx.y;
  const int wm = (wave >> 1) * 64;  // wave's M offset in tile
  const int wn = (wave & 1)  * 64;  // wave's N offset in tile

  // Staging: wave stages tile rows [wave*32, wave*32+32), 2 insts x 16 rows.
  // Lane l covers row (l>>2); global chunk = (l&3) ^ ((l>>4)&3) so that LDS
  // slot (l&3) holds chunk c at slot c ^ ((row>>2)&3).
  const int srow = wave * 32 + (lane >> 2);
  const int scol = (((lane & 3) ^ ((lane >> 4) & 3)) * 8);  // bf16 elements
  const u16* Ag = A + (size_t)(bm * BM + srow) * IN_F + scol;
  const u16* Wg = W + (size_t)(bn * BN + srow) * IN_F + scol;
  u16* AsW = (u16*)As + (wave * 32) * BK;  // wave-uniform LDS base
  u16* BsW = (u16*)Bs + (wave * 32) * BK;

  f32x4 acc[4][4];
#pragma unroll
  for (int mi = 0; mi < 4; ++mi)
#pragma unroll
    for (int ni = 0; ni < 4; ++ni) acc[mi][ni] = (f32x4){0.f, 0.f, 0.f, 0.f};

  const int fr = lane & 15;  // fragment row (m for A, n for B)
  const int fq = lane >> 4;  // quad -> k chunk (8 bf16 = 16B)
  const int slot = fq ^ ((fr >> 2) & 3);  // swizzled chunk slot for reads

  for (int kt = 0; kt < IN_F; kt += BK) {
    __syncthreads();  // previous iteration's ds_reads done before overwrite
    GLDS(Ag + kt,              AsW);
    GLDS(Ag + kt + 16 * IN_F,  AsW + 16 * BK);
    GLDS(Wg + kt,              BsW);
    GLDS(Wg + kt + 16 * IN_F,  BsW + 16 * BK);
    __syncthreads();  // compiler emits s_waitcnt vmcnt(0) before s_barrier

    bf16x8 af[4], bg[4];
#pragma unroll
    for (int mi = 0; mi < 4; ++mi)
      af[mi] = *(const bf16x8*)&As[(wm + mi * 16 + fr) * BK + slot * 8];
#pragma unroll
    for (int ni = 0; ni < 4; ++ni)
      bg[ni] = *(const bf16x8*)&Bs[(wn + ni * 16 + fr) * BK + slot * 8];
#pragma unroll
    for (int mi = 0; mi < 4; ++mi)
#pragma unroll
      for (int ni = 0; ni < 4; ++ni)
        acc[mi][ni] = __builtin_amdgcn_mfma_f32_16x16x32_bf16(
            af[mi], bg[ni], acc[mi][ni], 0, 0, 0);
  }

  // Epilogue: C/D layout col = lane&15 (n), row = (lane>>4)*4 + reg (m).
#pragma unroll
  for (int ni = 0; ni < 4; ++ni) {
    const int n = bn * BN + wn + ni * 16 + fr;
    const float bv = bias[n];
#pragma unroll
    for (int mi = 0; mi < 4; ++mi) {
      const int m0 = bm * BM + wm + mi * 16 + fq * 4;
#pragma unroll
      for (int rr = 0; rr < 4; ++rr)
        C[(size_t)(m0 + rr) * OUT_F + n] = acc[mi][ni][rr] + bv;
    }
  }
}

extern "C" void kernel_launch(void* const* d_in, const int* in_sizes, int n_in,
                              void* d_out, int out_size, void* d_ws, size_t ws_size,
                              hipStream_t stream) {
  const float* input = (const float*)d_in[0];  // (4,2048,4096) fp32
  const float* qw    = (const float*)d_in[1];  // (4096,3968) fp32
  const float* fpw   = (const float*)d_in[2];  // (4096,128) fp32
  const float* alpha = (const float*)d_in[3];  // (4096,1) fp32
  const float* bias  = (const float*)d_in[4];  // (4096,) fp32
  const int*   invp  = (const int*)d_in[5];    // (4096,) int32

  u16* Ab = (u16*)d_ws;                                     // 64 MB
  u16* W  = (u16*)((char*)d_ws + (size_t)MTOT * IN_F * 2);  // +32 MB
  float* out = (float*)d_out;                               // fp32

  prep_fused<<<NA_BLOCKS + OUT_F, 256, 0, stream>>>(input, Ab, qw, fpw,
                                                    alpha, invp, W);

  dim3 ggrid(OUT_F / BN, MTOT / BM);  // (32, 64)
  gemm_bt<<<ggrid, dim3(256), 0, stream>>>(Ab, W, bias, out);
}

// Round 4
// 475.577 us; speedup vs baseline: 1.3125x; 1.2106x over previous
//
#include <hip/hip_runtime.h>
#include <stdint.h>

// QuantizedLinear: B=4, S=2048, IN=4096, OUT=4096, OUTLIER=128
// out = s_m * alpha_o * (A_i8 . Q_i8^T) + A_fp . FP^T + bias
//   - q_weight is integers in [-8,8) -> EXACT in int8; alpha factored to epilogue
//   - A quantized per-row symmetric int8 (s_m = rowabsmax/127)
//   - 128 outlier columns -> K=128 bf16 tail fused into the same GEMM kernel
#define IN_F  4096
#define OUT_F 4096
#define OUTL  128
#define QIN   (IN_F - OUTL)   // 3968
#define MTOT  8192            // B*S
#define BM 128
#define BN 128

typedef unsigned short u16;
typedef __bf16 bf16x8 __attribute__((ext_vector_type(8)));
typedef float  f32x4  __attribute__((ext_vector_type(4)));
typedef int    i32x4  __attribute__((ext_vector_type(4)));

__device__ __forceinline__ u16 f2b(float f) {
  union { float f; uint32_t i; } v; v.f = f;
  uint32_t r = v.i + 0x7fffu + ((v.i >> 16) & 1u);  // round-to-nearest-even
  return (u16)(r >> 16);
}

// ---------------------------------------------------------------------------
// P0: pos[c] = i such that invp[i] == QIN + c  (the outlier source columns)
// ---------------------------------------------------------------------------
__global__ void build_pos(const int* __restrict__ invp, int* __restrict__ pos) {
  const int i = blockIdx.x * 256 + threadIdx.x;
  const int j = invp[i];
  if (j >= QIN) pos[j - QIN] = i;  // each c written exactly once: race-free
}

// ---------------------------------------------------------------------------
// P1: per-row A prep. One block per m-row: row absmax -> s_m, quantize row to
// int8 (coalesced dword stores), gather 128 outlier elements to bf16 A_fp.
// ---------------------------------------------------------------------------
__global__ __launch_bounds__(256) void prep_a(
    const float* __restrict__ A, const int* __restrict__ pos,
    signed char* __restrict__ A8, u16* __restrict__ Afp,
    float* __restrict__ s_arr) {
  const int m = blockIdx.x;
  const int tid = threadIdx.x;
  const float* row = A + (size_t)m * IN_F;

  float4 v[4];
  float amax = 0.f;
#pragma unroll
  for (int k = 0; k < 4; ++k) {
    v[k] = ((const float4*)row)[k * 256 + tid];
    amax = fmaxf(amax, fmaxf(fmaxf(fabsf(v[k].x), fabsf(v[k].y)),
                             fmaxf(fabsf(v[k].z), fabsf(v[k].w))));
  }
#pragma unroll
  for (int off = 32; off; off >>= 1)
    amax = fmaxf(amax, __shfl_xor(amax, off, 64));
  __shared__ float wmax[4];
  if ((tid & 63) == 0) wmax[tid >> 6] = amax;
  __syncthreads();
  amax = fmaxf(fmaxf(wmax[0], wmax[1]), fmaxf(wmax[2], wmax[3]));
  const float inv = (amax > 0.f) ? 127.f / amax : 0.f;
  if (tid == 0) s_arr[m] = amax / 127.f;

#pragma unroll
  for (int k = 0; k < 4; ++k) {
    const int q0 = __float2int_rn(v[k].x * inv);
    const int q1 = __float2int_rn(v[k].y * inv);
    const int q2 = __float2int_rn(v[k].z * inv);
    const int q3 = __float2int_rn(v[k].w * inv);
    const uint32_t p = (q0 & 255) | ((q1 & 255) << 8) |
                       ((q2 & 255) << 16) | ((uint32_t)(q3 & 255) << 24);
    ((uint32_t*)A8)[(size_t)m * (IN_F / 4) + k * 256 + tid] = p;
  }
  if (tid < OUTL) {
    const int p = pos[tid];                       // L2-hot
    Afp[(size_t)m * OUTL + tid] = f2b(row[p]);    // row is L1-hot
  }
}

// ---------------------------------------------------------------------------
// P2: per-o weight prep. W8[o,i] = invp[i]<QIN ? (int8)qw[o,invp[i]] : 0
// (exact: qw holds integers). Wfp[o,c] = bf16(fpw[o,c]). qw row staged in LDS.
// ---------------------------------------------------------------------------
__global__ __launch_bounds__(256) void prep_w(
    const float* __restrict__ qw, const float* __restrict__ fpw,
    const int* __restrict__ invp, signed char* __restrict__ W8,
    u16* __restrict__ Wfp) {
  __shared__ float qs[QIN];  // 15.9 KB
  const int o = blockIdx.x;
  const int tid = threadIdx.x;
  const float4* qrow = (const float4*)(qw + (size_t)o * QIN);
#pragma unroll
  for (int k = 0; k < 4; ++k) {
    const int idx = k * 256 + tid;
    if (idx < QIN / 4) ((float4*)qs)[idx] = qrow[idx];
  }
  __syncthreads();

  signed char vals[16];
#pragma unroll
  for (int q = 0; q < 4; ++q) {
    const int4 jj = ((const int4*)invp)[tid * 4 + q];
    const int j[4] = {jj.x, jj.y, jj.z, jj.w};
#pragma unroll
    for (int e = 0; e < 4; ++e)
      vals[q * 4 + e] =
          (j[e] < QIN) ? (signed char)__float2int_rn(qs[j[e]]) : (signed char)0;
  }
  ((uint4*)(W8 + (size_t)o * IN_F))[tid] = *(const uint4*)vals;
  if (tid < OUTL)
    Wfp[(size_t)o * OUTL + tid] = f2b(fpw[(size_t)o * OUTL + tid]);
}

// ---------------------------------------------------------------------------
// GEMM: m97 structure. Main loop: 64 iters of i8 16x16x64 (BK=64 bytes/row,
// same 64B LDS row geometry as the bf16 version). Tail: 4 iters of bf16
// 16x16x32 over the outlier K=128, reusing the same LDS. Epilogue combines:
// C = s_m*alpha_n*(float)acc_i32 + acc_fp + bias_n.
// ---------------------------------------------------------------------------
#define GLDS(g, l)                                                              \
  __builtin_amdgcn_global_load_lds(                                             \
      (const __attribute__((address_space(1))) void*)(g),                       \
      (__attribute__((address_space(3))) void*)(l), 16, 0, 0)

__global__ __launch_bounds__(256) void gemm_i8(
    const signed char* __restrict__ A8, const signed char* __restrict__ W8,
    const u16* __restrict__ Afp, const u16* __restrict__ Wfp,
    const float* __restrict__ s_arr, const float* __restrict__ alpha,
    const float* __restrict__ bias, float* __restrict__ C) {
  __shared__ unsigned char As8[BM * 64];  // 8 KB
  __shared__ unsigned char Bs8[BN * 64];  // 8 KB

  const int tid  = threadIdx.x;
  const int wave = tid >> 6;
  const int lane = tid & 63;
  const int bn = blockIdx.x, bm = blockIdx.y;
  const int wm = (wave >> 1) * 64;
  const int wn = (wave & 1)  * 64;

  // Staging: rows are 64 B; lane l -> row (l>>2), 16B chunk (l&3) XOR-swizzled.
  const int srow   = wave * 32 + (lane >> 2);
  const int schunk = (lane & 3) ^ ((lane >> 4) & 3);
  const signed char* Ag = A8 + (size_t)(bm * BM + srow) * IN_F + schunk * 16;
  const signed char* Wg = W8 + (size_t)(bn * BN + srow) * IN_F + schunk * 16;
  unsigned char* AsW = As8 + wave * 32 * 64;
  unsigned char* BsW = Bs8 + wave * 32 * 64;

  i32x4 acci[4][4];
#pragma unroll
  for (int mi = 0; mi < 4; ++mi)
#pragma unroll
    for (int ni = 0; ni < 4; ++ni) acci[mi][ni] = (i32x4){0, 0, 0, 0};

  const int fr = lane & 15;              // fragment row (m for A, n for B)
  const int fq = lane >> 4;              // quad -> 16B k-chunk
  const int slot = fq ^ ((fr >> 2) & 3); // swizzled chunk slot

  for (int kt = 0; kt < IN_F / 64; ++kt) {
    __syncthreads();
    GLDS(Ag + kt * 64,               AsW);
    GLDS(Ag + kt * 64 + 16 * IN_F,   AsW + 16 * 64);
    GLDS(Wg + kt * 64,               BsW);
    GLDS(Wg + kt * 64 + 16 * IN_F,   BsW + 16 * 64);
    __syncthreads();

    i32x4 af[4], bg[4];
#pragma unroll
    for (int mi = 0; mi < 4; ++mi)
      af[mi] = *(const i32x4*)&As8[(wm + mi * 16 + fr) * 64 + slot * 16];
#pragma unroll
    for (int ni = 0; ni < 4; ++ni)
      bg[ni] = *(const i32x4*)&Bs8[(wn + ni * 16 + fr) * 64 + slot * 16];
#pragma unroll
    for (int mi = 0; mi < 4; ++mi)
#pragma unroll
      for (int ni = 0; ni < 4; ++ni)
        acci[mi][ni] = __builtin_amdgcn_mfma_i32_16x16x64_i8(
            af[mi], bg[ni], acci[mi][ni], 0, 0, 0);
  }

  // ---- bf16 outlier tail: K=128 in 4 chunks of 32 (rows still 64 B) ----
  f32x4 accf[4][4];
#pragma unroll
  for (int mi = 0; mi < 4; ++mi)
#pragma unroll
    for (int ni = 0; ni < 4; ++ni) accf[mi][ni] = (f32x4){0.f, 0.f, 0.f, 0.f};

  u16* AsH = (u16*)As8;  // viewed as 128 x 32 u16
  u16* BsH = (u16*)Bs8;
  const u16* Afg = Afp + (size_t)(bm * BM + srow) * OUTL + schunk * 8;
  const u16* Wfg = Wfp + (size_t)(bn * BN + srow) * OUTL + schunk * 8;
  u16* AsWH = AsH + wave * 32 * 32;
  u16* BsWH = BsH + wave * 32 * 32;

  for (int kt = 0; kt < 4; ++kt) {
    __syncthreads();
    GLDS(Afg + kt * 32,              AsWH);
    GLDS(Afg + kt * 32 + 16 * OUTL,  AsWH + 16 * 32);
    GLDS(Wfg + kt * 32,              BsWH);
    GLDS(Wfg + kt * 32 + 16 * OUTL,  BsWH + 16 * 32);
    __syncthreads();

    bf16x8 af[4], bg[4];
#pragma unroll
    for (int mi = 0; mi < 4; ++mi)
      af[mi] = *(const bf16x8*)&AsH[(wm + mi * 16 + fr) * 32 + slot * 8];
#pragma unroll
    for (int ni = 0; ni < 4; ++ni)
      bg[ni] = *(const bf16x8*)&BsH[(wn + ni * 16 + fr) * 32 + slot * 8];
#pragma unroll
    for (int mi = 0; mi < 4; ++mi)
#pragma unroll
      for (int ni = 0; ni < 4; ++ni)
        accf[mi][ni] = __builtin_amdgcn_mfma_f32_16x16x32_bf16(
            af[mi], bg[ni], accf[mi][ni], 0, 0, 0);
  }

  // ---- epilogue: C/D layout col = lane&15 (n), row = (lane>>4)*4 + reg (m)
  float sv[4][4];
#pragma unroll
  for (int mi = 0; mi < 4; ++mi)
#pragma unroll
    for (int rr = 0; rr < 4; ++rr)
      sv[mi][rr] = s_arr[bm * BM + wm + mi * 16 + fq * 4 + rr];

#pragma unroll
  for (int ni = 0; ni < 4; ++ni) {
    const int n = bn * BN + wn + ni * 16 + fr;
    const float an = alpha[n];
    const float bv = bias[n];
#pragma unroll
    for (int mi = 0; mi < 4; ++mi) {
      const int m0 = bm * BM + wm + mi * 16 + fq * 4;
#pragma unroll
      for (int rr = 0; rr < 4; ++rr)
        C[(size_t)(m0 + rr) * OUT_F + n] =
            (float)acci[mi][ni][rr] * (sv[mi][rr] * an) + accf[mi][ni][rr] + bv;
    }
  }
}

extern "C" void kernel_launch(void* const* d_in, const int* in_sizes, int n_in,
                              void* d_out, int out_size, void* d_ws, size_t ws_size,
                              hipStream_t stream) {
  const float* input = (const float*)d_in[0];  // (4,2048,4096) fp32
  const float* qw    = (const float*)d_in[1];  // (4096,3968) fp32
  const float* fpw   = (const float*)d_in[2];  // (4096,128) fp32
  const float* alpha = (const float*)d_in[3];  // (4096,1) fp32
  const float* bias  = (const float*)d_in[4];  // (4096,) fp32
  const int*   invp  = (const int*)d_in[5];    // (4096,) int32

  char* ws = (char*)d_ws;
  signed char* A8   = (signed char*)ws;                         // 32 MB
  signed char* W8   = (signed char*)(ws + (32ull << 20));       // 16 MB
  u16*  Afp  = (u16*)(ws + (48ull << 20));                      //  2 MB
  u16*  Wfp  = (u16*)(ws + (50ull << 20));                      //  1 MB
  float* s_arr = (float*)(ws + (51ull << 20));                  // 32 KB
  int*   pos   = (int*)(ws + (51ull << 20) + (64ull << 10));    // 512 B
  float* out = (float*)d_out;

  build_pos<<<IN_F / 256, 256, 0, stream>>>(invp, pos);
  prep_a<<<MTOT, 256, 0, stream>>>(input, pos, A8, Afp, s_arr);
  prep_w<<<OUT_F, 256, 0, stream>>>(qw, fpw, invp, W8, Wfp);

  dim3 ggrid(OUT_F / BN, MTOT / BM);  // (32, 64)
  gemm_i8<<<ggrid, dim3(256), 0, stream>>>(A8, W8, Afp, Wfp, s_arr, alpha,
                                           bias, out);
}

// Round 5
// 403.324 us; speedup vs baseline: 1.5477x; 1.1791x over previous
//
#include <hip/hip_runtime.h>
#include <stdint.h>

// QuantizedLinear: B=4, S=2048, IN=4096, OUT=4096, OUTLIER=128
// Unified int8 path:
//   W8[o,i] = round(w[o, invp[i]] / w_s_o),  w[o,:] = [qw*alpha | fpw] permuted
//   w_s_o   = rowabsmax(w[o,:]) / 127        (per-output-row scale)
//   A8[m,i] = round(A[m,i] / s_m),  s_m = rowabsmax / 127
//   out[m,o] = s_m * w_s_o * (A8 . W8^T)[m,o] + bias[o]
#define IN_F  4096
#define OUT_F 4096
#define OUTL  128
#define QIN   (IN_F - OUTL)   // 3968
#define MTOT  8192            // B*S
#define BM 128
#define BN 128
#define BKB 128               // K-bytes per LDS row per iteration

typedef unsigned short u16;
typedef int i32x4 __attribute__((ext_vector_type(4)));

// ---------------------------------------------------------------------------
// Fused prep. Blocks [0, OUT_F): weight rows. Blocks [OUT_F, OUT_F+MTOT):
// activation rows. All global reads coalesced float4; stores coalesced 16B.
// ---------------------------------------------------------------------------
__global__ __launch_bounds__(256) void prep_fused(
    const float* __restrict__ A, signed char* __restrict__ A8,
    float* __restrict__ s_arr,
    const float* __restrict__ qw, const float* __restrict__ fpw,
    const float* __restrict__ alpha, const int* __restrict__ invp,
    signed char* __restrict__ W8, float* __restrict__ t_arr) {
  const int tid = threadIdx.x;
  __shared__ float red[4];

  if (blockIdx.x >= OUT_F) {
    // ---- activation row: absmax -> s_m, quantize to int8 ----
    const int m = blockIdx.x - OUT_F;
    const float* row = A + (size_t)m * IN_F;
    float4 v[4];
    float amax = 0.f;
#pragma unroll
    for (int k = 0; k < 4; ++k) {
      v[k] = ((const float4*)row)[k * 256 + tid];
      amax = fmaxf(amax, fmaxf(fmaxf(fabsf(v[k].x), fabsf(v[k].y)),
                               fmaxf(fabsf(v[k].z), fabsf(v[k].w))));
    }
#pragma unroll
    for (int off = 32; off; off >>= 1)
      amax = fmaxf(amax, __shfl_xor(amax, off, 64));
    if ((tid & 63) == 0) red[tid >> 6] = amax;
    __syncthreads();
    amax = fmaxf(fmaxf(red[0], red[1]), fmaxf(red[2], red[3]));
    const float inv = 127.f / amax;
    if (tid == 0) s_arr[m] = amax / 127.f;
#pragma unroll
    for (int k = 0; k < 4; ++k) {
      const int q0 = __float2int_rn(v[k].x * inv);
      const int q1 = __float2int_rn(v[k].y * inv);
      const int q2 = __float2int_rn(v[k].z * inv);
      const int q3 = __float2int_rn(v[k].w * inv);
      const uint32_t p = (q0 & 255) | ((q1 & 255) << 8) |
                         ((q2 & 255) << 16) | ((uint32_t)(q3 & 255) << 24);
      ((uint32_t*)A8)[(size_t)m * (IN_F / 4) + k * 256 + tid] = p;
    }
  } else {
    // ---- weight row: stage qw/fpw in LDS, rowabsmax of [qw*a | fpw],
    //      permuted gather, quantize to int8 ----
    const int o = blockIdx.x;
    __shared__ float qs[QIN];   // 15.9 KB
    __shared__ float fs[OUTL];
    const float a = alpha[o];
    float amax = 0.f;
    const float4* qrow = (const float4*)(qw + (size_t)o * QIN);
#pragma unroll
    for (int k = 0; k < 4; ++k) {
      const int idx = k * 256 + tid;
      if (idx < QIN / 4) {
        const float4 q = qrow[idx];
        ((float4*)qs)[idx] = q;
        const float qm = fmaxf(fmaxf(fabsf(q.x), fabsf(q.y)),
                               fmaxf(fabsf(q.z), fabsf(q.w)));
        amax = fmaxf(amax, qm * a);
      }
    }
    if (tid < OUTL / 4) {
      const float4 f = ((const float4*)(fpw + (size_t)o * OUTL))[tid];
      ((float4*)fs)[tid] = f;
      amax = fmaxf(amax, fmaxf(fmaxf(fabsf(f.x), fabsf(f.y)),
                               fmaxf(fabsf(f.z), fabsf(f.w))));
    }
#pragma unroll
    for (int off = 32; off; off >>= 1)
      amax = fmaxf(amax, __shfl_xor(amax, off, 64));
    if ((tid & 63) == 0) red[tid >> 6] = amax;
    __syncthreads();  // also covers qs/fs visibility
    amax = fmaxf(fmaxf(red[0], red[1]), fmaxf(red[2], red[3]));
    const float invws = 127.f / amax;
    if (tid == 0) t_arr[o] = amax / 127.f;

    signed char vals[16];
#pragma unroll
    for (int q = 0; q < 4; ++q) {
      const int4 jj = ((const int4*)invp)[tid * 4 + q];
      const int j[4] = {jj.x, jj.y, jj.z, jj.w};
#pragma unroll
      for (int e = 0; e < 4; ++e) {
        const float v = (j[e] < QIN) ? qs[j[e]] * a : fs[j[e] - QIN];
        vals[q * 4 + e] = (signed char)__float2int_rn(v * invws);
      }
    }
    ((uint4*)(W8 + (size_t)o * IN_F))[tid] = *(const uint4*)vals;
  }
}

// ---------------------------------------------------------------------------
// GEMM: single i8 K=4096 loop, BK=128 bytes/row (32 iters, 66 barriers).
// Rows are 128 B = 8 x 16B chunks; chunk c of row r stored at slot c^(r&7)
// -> fragment reads are 2-way bank aliased (free). k-split (ks=0,1) reuses
// fragment registers so live regs stay ~150 -> 3 waves/SIMD.
// ---------------------------------------------------------------------------
#define GLDS(g, l)                                                              \
  __builtin_amdgcn_global_load_lds(                                             \
      (const __attribute__((address_space(1))) void*)(g),                       \
      (__attribute__((address_space(3))) void*)(l), 16, 0, 0)

__global__ __launch_bounds__(256, 3) void gemm_i8(
    const signed char* __restrict__ A8, const signed char* __restrict__ W8,
    const float* __restrict__ s_arr, const float* __restrict__ t_arr,
    const float* __restrict__ bias, float* __restrict__ C) {
  __shared__ unsigned char As8[BM * BKB];  // 16 KB
  __shared__ unsigned char Bs8[BN * BKB];  // 16 KB

  const int tid  = threadIdx.x;
  const int wave = tid >> 6;
  const int lane = tid & 63;
  const int bn = blockIdx.x, bm = blockIdx.y;
  const int wm = (wave >> 1) * 64;
  const int wn = (wave & 1)  * 64;

  // Staging: lane l -> row (l>>3) within an 8-row group, chunk (l&7) XOR'd by
  // row so LDS slot s of row r holds global chunk s^(r&7). Each GLDS covers
  // 8 rows x 128 B = 1 KB; 4 insts per tile per wave.
  const int srow   = wave * 32 + (lane >> 3);
  const int schunk = (lane & 7) ^ ((lane >> 3) & 7);
  const signed char* Ag = A8 + (size_t)(bm * BM + srow) * IN_F + schunk * 16;
  const signed char* Wg = W8 + (size_t)(bn * BN + srow) * IN_F + schunk * 16;
  unsigned char* AsW = As8 + wave * 32 * BKB;
  unsigned char* BsW = Bs8 + wave * 32 * BKB;

  i32x4 acc[4][4];
#pragma unroll
  for (int mi = 0; mi < 4; ++mi)
#pragma unroll
    for (int ni = 0; ni < 4; ++ni) acc[mi][ni] = (i32x4){0, 0, 0, 0};

  const int fr = lane & 15;  // fragment row (m for A, n for B)
  const int fq = lane >> 4;  // quad -> 16B k-chunk within 64B k-step

  for (int kt = 0; kt < IN_F / BKB; ++kt) {  // 32 iterations
    __syncthreads();
#pragma unroll
    for (int t = 0; t < 4; ++t) {
      GLDS(Ag + kt * BKB + t * 8 * IN_F, AsW + t * 8 * BKB);
      GLDS(Wg + kt * BKB + t * 8 * IN_F, BsW + t * 8 * BKB);
    }
    __syncthreads();

#pragma unroll
    for (int ks = 0; ks < 2; ++ks) {
      i32x4 af[4], bg[4];
#pragma unroll
      for (int mi = 0; mi < 4; ++mi)
        af[mi] = *(const i32x4*)
            &As8[(wm + mi * 16 + fr) * BKB + (((ks * 4 + fq) ^ (fr & 7)) * 16)];
#pragma unroll
      for (int ni = 0; ni < 4; ++ni)
        bg[ni] = *(const i32x4*)
            &Bs8[(wn + ni * 16 + fr) * BKB + (((ks * 4 + fq) ^ (fr & 7)) * 16)];
#pragma unroll
      for (int mi = 0; mi < 4; ++mi)
#pragma unroll
        for (int ni = 0; ni < 4; ++ni)
          acc[mi][ni] = __builtin_amdgcn_mfma_i32_16x16x64_i8(
              af[mi], bg[ni], acc[mi][ni], 0, 0, 0);
    }
  }

  // Epilogue: C/D layout col = lane&15 (n), row = (lane>>4)*4 + reg (m).
  float sv[4][4];
#pragma unroll
  for (int mi = 0; mi < 4; ++mi)
#pragma unroll
    for (int rr = 0; rr < 4; ++rr)
      sv[mi][rr] = s_arr[bm * BM + wm + mi * 16 + fq * 4 + rr];

#pragma unroll
  for (int ni = 0; ni < 4; ++ni) {
    const int n = bn * BN + wn + ni * 16 + fr;
    const float tn = t_arr[n];
    const float bv = bias[n];
#pragma unroll
    for (int mi = 0; mi < 4; ++mi) {
      const int m0 = bm * BM + wm + mi * 16 + fq * 4;
#pragma unroll
      for (int rr = 0; rr < 4; ++rr)
        C[(size_t)(m0 + rr) * OUT_F + n] =
            (float)acc[mi][ni][rr] * (sv[mi][rr] * tn) + bv;
    }
  }
}

extern "C" void kernel_launch(void* const* d_in, const int* in_sizes, int n_in,
                              void* d_out, int out_size, void* d_ws, size_t ws_size,
                              hipStream_t stream) {
  const float* input = (const float*)d_in[0];  // (4,2048,4096) fp32
  const float* qw    = (const float*)d_in[1];  // (4096,3968) fp32
  const float* fpw   = (const float*)d_in[2];  // (4096,128) fp32
  const float* alpha = (const float*)d_in[3];  // (4096,1) fp32
  const float* bias  = (const float*)d_in[4];  // (4096,) fp32
  const int*   invp  = (const int*)d_in[5];    // (4096,) int32

  char* ws = (char*)d_ws;
  signed char* A8    = (signed char*)ws;                        // 32 MB
  signed char* W8    = (signed char*)(ws + (32ull << 20));      // 16 MB
  float* s_arr = (float*)(ws + (48ull << 20));                  // 32 KB
  float* t_arr = (float*)(ws + (48ull << 20) + (64ull << 10));  // 16 KB
  float* out = (float*)d_out;

  prep_fused<<<OUT_F + MTOT, 256, 0, stream>>>(input, A8, s_arr, qw, fpw,
                                               alpha, invp, W8, t_arr);

  dim3 ggrid(OUT_F / BN, MTOT / BM);  // (32, 64)
  gemm_i8<<<ggrid, dim3(256), 0, stream>>>(A8, W8, s_arr, t_arr, bias, out);
}